// Round 1
// baseline (1073.425 us; speedup 1.0000x reference)
//
#include <hip/hip_runtime.h>
#include <math.h>

#define NN 50000
#define CC 256
#define HH 4
#define DD 64
#define EE 800000
#define EPS 1e-5f
#define SLOPE 0.2f

// ---------------- K1: BN (inference) -> ReLU -> mask; also out = h + bias ----------------
__global__ void bn_relu_kernel(const float* __restrict__ x, const float* __restrict__ mask,
                               const float* __restrict__ gamma, const float* __restrict__ beta,
                               const float* __restrict__ mean, const float* __restrict__ var,
                               const float* __restrict__ bias, float* __restrict__ h,
                               float* __restrict__ out) {
    int i = blockIdx.x * 256 + threadIdx.x;          // index into N*C/4 float4s
    const int total = NN * CC / 4;
    if (i >= total) return;
    float4 xv = ((const float4*)x)[i];
    float4 mv = ((const float4*)mask)[i];
    int c0 = (i & (CC / 4 - 1)) * 4;                 // channel base 0..252
    float4 hv, ov;
    {
        float s = gamma[c0 + 0] * rsqrtf(var[c0 + 0] + EPS);
        float v = (xv.x - mean[c0 + 0]) * s + beta[c0 + 0];
        hv.x = fmaxf(v, 0.f) * mv.x; ov.x = hv.x + bias[c0 + 0];
    }
    {
        float s = gamma[c0 + 1] * rsqrtf(var[c0 + 1] + EPS);
        float v = (xv.y - mean[c0 + 1]) * s + beta[c0 + 1];
        hv.y = fmaxf(v, 0.f) * mv.y; ov.y = hv.y + bias[c0 + 1];
    }
    {
        float s = gamma[c0 + 2] * rsqrtf(var[c0 + 2] + EPS);
        float v = (xv.z - mean[c0 + 2]) * s + beta[c0 + 2];
        hv.z = fmaxf(v, 0.f) * mv.z; ov.z = hv.z + bias[c0 + 2];
    }
    {
        float s = gamma[c0 + 3] * rsqrtf(var[c0 + 3] + EPS);
        float v = (xv.w - mean[c0 + 3]) * s + beta[c0 + 3];
        hv.w = fmaxf(v, 0.f) * mv.w; ov.w = hv.w + bias[c0 + 3];
    }
    ((float4*)h)[i] = hv;
    ((float4*)out)[i] = ov;
}

// ---------------- K2: feat[N,512] = h @ [fc_w | fc_dst_w]^T  (fp32 tiled SGEMM) ----------------
// W is [256 out][256 k] row-major; feat[n][o] = sum_k h[n][k]*W[o][k]
__global__ __launch_bounds__(256) void gemm_kernel(const float* __restrict__ Ah,
                                                   const float* __restrict__ W0,
                                                   const float* __restrict__ W1,
                                                   float* __restrict__ feat) {
    const int bx = blockIdx.x;                 // row tile (64 rows)
    const int by = blockIdx.y;                 // col tile (64 cols of 512)
    const float* Wp = (by < 4) ? W0 : W1;
    const int oc0 = (by & 3) * 64;

    __shared__ float sA[64][17];               // [row][k]
    __shared__ float sB[16][68];               // [k][col]

    const int tid = threadIdx.x;
    const int tx = tid & 15, ty = tid >> 4;
    const int row0 = bx * 64;
    float acc[4][4] = {};

    for (int k0 = 0; k0 < 256; k0 += 16) {
#pragma unroll
        for (int i = 0; i < 4; ++i) {          // load A 64x16
            int e = tid + i * 256;
            int r = e >> 4, kk = e & 15;
            int gr = row0 + r;
            sA[r][kk] = (gr < NN) ? Ah[gr * 256 + k0 + kk] : 0.f;
        }
#pragma unroll
        for (int i = 0; i < 4; ++i) {          // load B 16x64 (W[o][k] -> sB[k][c])
            int e = tid + i * 256;
            int cc = e >> 4, kk = e & 15;
            sB[kk][cc] = Wp[(oc0 + cc) * 256 + k0 + kk];
        }
        __syncthreads();
#pragma unroll
        for (int kk = 0; kk < 16; ++kk) {
            float a[4], b[4];
#pragma unroll
            for (int i = 0; i < 4; ++i) a[i] = sA[ty * 4 + i][kk];
#pragma unroll
            for (int j = 0; j < 4; ++j) b[j] = sB[kk][tx * 4 + j];
#pragma unroll
            for (int i = 0; i < 4; ++i)
#pragma unroll
                for (int j = 0; j < 4; ++j) acc[i][j] = fmaf(a[i], b[j], acc[i][j]);
        }
        __syncthreads();
    }
#pragma unroll
    for (int i = 0; i < 4; ++i) {
        int gr = row0 + ty * 4 + i;
        if (gr < NN) {
#pragma unroll
            for (int j = 0; j < 4; ++j)
                feat[gr * 512 + by * 64 + tx * 4 + j] = acc[i][j];
        }
    }
}

// ---------------- K3: el[n][h], er[n][h] per-node attention logits ----------------
__global__ void elr_kernel(const float* __restrict__ feat, const float* __restrict__ attn_l,
                           const float* __restrict__ attn_r, float* __restrict__ el,
                           float* __restrict__ er) {
    int n = blockIdx.x;
    int t = threadIdx.x;                       // 256 threads; wave w handles head w
    int hh = t >> 6, d = t & 63;
    float pl = feat[n * 512 + t] * attn_l[t];
    float pr = feat[n * 512 + 256 + t] * attn_r[t];
#pragma unroll
    for (int off = 32; off; off >>= 1) {
        pl += __shfl_down(pl, off, 64);
        pr += __shfl_down(pr, off, 64);
    }
    if (d == 0) {
        el[n * 4 + hh] = pl;
        er[n * 4 + hh] = pr;
    }
}

// ---------------- K4: per-edge w = exp(leaky_relu(el[src]+er[dst])); denom[dst] += w --------
__global__ void edge_w_kernel(const int* __restrict__ src, const int* __restrict__ dst,
                              const float* __restrict__ el, const float* __restrict__ er,
                              float* __restrict__ w, float* __restrict__ denom) {
    int e = blockIdx.x * 256 + threadIdx.x;
    if (e >= EE) return;
    int s = src[e], dd = dst[e];
    float4 a = ((const float4*)el)[s];
    float4 b = ((const float4*)er)[dd];
    float4 wv;
    float v;
    v = a.x + b.x; v = (v > 0.f) ? v : SLOPE * v; wv.x = expf(v);
    v = a.y + b.y; v = (v > 0.f) ? v : SLOPE * v; wv.y = expf(v);
    v = a.z + b.z; v = (v > 0.f) ? v : SLOPE * v; wv.z = expf(v);
    v = a.w + b.w; v = (v > 0.f) ? v : SLOPE * v; wv.w = expf(v);
    ((float4*)w)[e] = wv;
    atomicAdd(&denom[dd * 4 + 0], wv.x);
    atomicAdd(&denom[dd * 4 + 1], wv.y);
    atomicAdd(&denom[dd * 4 + 2], wv.z);
    atomicAdd(&denom[dd * 4 + 3], wv.w);
}

// ---------------- K5: out[dst] += (w/denom[dst]) * feat_src[src]  (one wave per edge) -------
__global__ void aggregate_kernel(const int* __restrict__ src, const int* __restrict__ dst,
                                 const float* __restrict__ w, const float* __restrict__ denom,
                                 const float* __restrict__ feat, float* __restrict__ out) {
    int gw = (blockIdx.x * 256 + threadIdx.x) >> 6;   // global wave id = edge id
    int lane = threadIdx.x & 63;
    if (gw >= EE) return;
    int s = src[gw], dd = dst[gw];
    float4 wv = ((const float4*)w)[gw];
    float4 dv = ((const float4*)denom)[dd];
    float c0 = wv.x / dv.x, c1 = wv.y / dv.y, c2 = wv.z / dv.z, c3 = wv.w / dv.w;
    const float* fs = feat + (long)s * 512;           // src half = first 256 cols
    float* o = out + (long)dd * 256;
    atomicAdd(&o[lane], c0 * fs[lane]);
    atomicAdd(&o[64 + lane], c1 * fs[64 + lane]);
    atomicAdd(&o[128 + lane], c2 * fs[128 + lane]);
    atomicAdd(&o[192 + lane], c3 * fs[192 + lane]);
}

extern "C" void kernel_launch(void* const* d_in, const int* in_sizes, int n_in,
                              void* d_out, int out_size, void* d_ws, size_t ws_size,
                              hipStream_t stream) {
    const float* x        = (const float*)d_in[0];
    const int*   eidx     = (const int*)d_in[1];
    const float* mask     = (const float*)d_in[2];
    const float* gamma    = (const float*)d_in[3];
    const float* beta     = (const float*)d_in[4];
    const float* mean     = (const float*)d_in[5];
    const float* var      = (const float*)d_in[6];
    const float* fc_w     = (const float*)d_in[7];
    const float* fc_dst_w = (const float*)d_in[8];
    const float* attn_l   = (const float*)d_in[9];
    const float* attn_r   = (const float*)d_in[10];
    const float* bias     = (const float*)d_in[11];
    float* out = (float*)d_out;

    const int* src = eidx;
    const int* dst = eidx + EE;

    float* ws_f  = (float*)d_ws;
    float* h     = ws_f;                        // N*256
    float* feat  = h + (size_t)NN * 256;        // N*512
    float* el    = feat + (size_t)NN * 512;     // N*4
    float* er    = el + (size_t)NN * 4;         // N*4
    float* w     = er + (size_t)NN * 4;         // E*4
    float* denom = w + (size_t)EE * 4;          // N*4

    // K1: h + out-init
    bn_relu_kernel<<<(NN * CC / 4 + 255) / 256, 256, 0, stream>>>(
        x, mask, gamma, beta, mean, var, bias, h, out);

    // K2: feat = h @ [fc_w | fc_dst_w]^T
    dim3 ggrid((NN + 63) / 64, 8);
    gemm_kernel<<<ggrid, 256, 0, stream>>>(h, fc_w, fc_dst_w, feat);

    // K3: el/er
    elr_kernel<<<NN, 256, 0, stream>>>(feat, attn_l, attn_r, el, er);

    // zero denom
    hipMemsetAsync(denom, 0, (size_t)NN * 4 * sizeof(float), stream);

    // K4: edge weights + denom
    edge_w_kernel<<<EE / 256, 256, 0, stream>>>(src, dst, el, er, w, denom);

    // K5: aggregate into out (out already holds h + bias)
    aggregate_kernel<<<EE / 4, 256, 0, stream>>>(src, dst, w, denom, feat, out);
}

// Round 2
// 555.240 us; speedup vs baseline: 1.9333x; 1.9333x over previous
//
#include <hip/hip_runtime.h>
#include <math.h>

#define NN 50000
#define CC 256
#define HH 4
#define DD 64
#define EE 800000
#define EPS 1e-5f
#define SLOPE 0.2f

// ---------------- K1: BN (inference) -> ReLU -> mask -> h ----------------
__global__ void bn_relu_kernel(const float* __restrict__ x, const float* __restrict__ mask,
                               const float* __restrict__ gamma, const float* __restrict__ beta,
                               const float* __restrict__ mean, const float* __restrict__ var,
                               float* __restrict__ h) {
    int i = blockIdx.x * 256 + threadIdx.x;          // index into N*C/4 float4s
    const int total = NN * CC / 4;
    if (i >= total) return;
    float4 xv = ((const float4*)x)[i];
    float4 mv = ((const float4*)mask)[i];
    int c0 = (i & (CC / 4 - 1)) * 4;                 // channel base 0..252
    float4 hv;
    {
        float s = gamma[c0 + 0] * rsqrtf(var[c0 + 0] + EPS);
        float v = (xv.x - mean[c0 + 0]) * s + beta[c0 + 0];
        hv.x = fmaxf(v, 0.f) * mv.x;
    }
    {
        float s = gamma[c0 + 1] * rsqrtf(var[c0 + 1] + EPS);
        float v = (xv.y - mean[c0 + 1]) * s + beta[c0 + 1];
        hv.y = fmaxf(v, 0.f) * mv.y;
    }
    {
        float s = gamma[c0 + 2] * rsqrtf(var[c0 + 2] + EPS);
        float v = (xv.z - mean[c0 + 2]) * s + beta[c0 + 2];
        hv.z = fmaxf(v, 0.f) * mv.z;
    }
    {
        float s = gamma[c0 + 3] * rsqrtf(var[c0 + 3] + EPS);
        float v = (xv.w - mean[c0 + 3]) * s + beta[c0 + 3];
        hv.w = fmaxf(v, 0.f) * mv.w;
    }
    ((float4*)h)[i] = hv;
}

// ---------------- K2: feat[N,512] = h @ [fc_w | fc_dst_w]^T  (fp32 tiled SGEMM) ----------------
__global__ __launch_bounds__(256) void gemm_kernel(const float* __restrict__ Ah,
                                                   const float* __restrict__ W0,
                                                   const float* __restrict__ W1,
                                                   float* __restrict__ feat) {
    const int bx = blockIdx.x;                 // row tile (64 rows)
    const int by = blockIdx.y;                 // col tile (64 cols of 512)
    const float* Wp = (by < 4) ? W0 : W1;
    const int oc0 = (by & 3) * 64;

    __shared__ float sA[64][17];               // [row][k]
    __shared__ float sB[16][68];               // [k][col]

    const int tid = threadIdx.x;
    const int tx = tid & 15, ty = tid >> 4;
    const int row0 = bx * 64;
    float acc[4][4] = {};

    for (int k0 = 0; k0 < 256; k0 += 16) {
#pragma unroll
        for (int i = 0; i < 4; ++i) {          // load A 64x16
            int e = tid + i * 256;
            int r = e >> 4, kk = e & 15;
            int gr = row0 + r;
            sA[r][kk] = (gr < NN) ? Ah[gr * 256 + k0 + kk] : 0.f;
        }
#pragma unroll
        for (int i = 0; i < 4; ++i) {          // load B 16x64 (W[o][k] -> sB[k][c])
            int e = tid + i * 256;
            int cc = e >> 4, kk = e & 15;
            sB[kk][cc] = Wp[(oc0 + cc) * 256 + k0 + kk];
        }
        __syncthreads();
#pragma unroll
        for (int kk = 0; kk < 16; ++kk) {
            float a[4], b[4];
#pragma unroll
            for (int i = 0; i < 4; ++i) a[i] = sA[ty * 4 + i][kk];
#pragma unroll
            for (int j = 0; j < 4; ++j) b[j] = sB[kk][tx * 4 + j];
#pragma unroll
            for (int i = 0; i < 4; ++i)
#pragma unroll
                for (int j = 0; j < 4; ++j) acc[i][j] = fmaf(a[i], b[j], acc[i][j]);
        }
        __syncthreads();
    }
#pragma unroll
    for (int i = 0; i < 4; ++i) {
        int gr = row0 + ty * 4 + i;
        if (gr < NN) {
#pragma unroll
            for (int j = 0; j < 4; ++j)
                feat[gr * 512 + by * 64 + tx * 4 + j] = acc[i][j];
        }
    }
}

// ---------------- K3: el[n][h], er[n][h] per-node attention logits ----------------
__global__ void elr_kernel(const float* __restrict__ feat, const float* __restrict__ attn_l,
                           const float* __restrict__ attn_r, float* __restrict__ el,
                           float* __restrict__ er) {
    int n = blockIdx.x;
    int t = threadIdx.x;                       // 256 threads; wave w handles head w
    int hh = t >> 6, d = t & 63;
    float pl = feat[n * 512 + t] * attn_l[t];
    float pr = feat[n * 512 + 256 + t] * attn_r[t];
#pragma unroll
    for (int off = 32; off; off >>= 1) {
        pl += __shfl_down(pl, off, 64);
        pr += __shfl_down(pr, off, 64);
    }
    if (d == 0) {
        el[n * 4 + hh] = pl;
        er[n * 4 + hh] = pr;
    }
}

// ---------------- CSR build: count incoming edges per dst ----------------
__global__ void count_kernel(const int* __restrict__ dst, int* __restrict__ counts) {
    int e = blockIdx.x * 256 + threadIdx.x;
    if (e >= EE) return;
    atomicAdd(&counts[dst[e]], 1);
}

// ---------------- CSR build: single-block exclusive scan of counts -> row_ptr ----------------
__global__ __launch_bounds__(1024) void scan_kernel(const int* __restrict__ counts,
                                                    int* __restrict__ row_ptr) {
    __shared__ int lds[1024];
    const int t = threadIdx.x;
    const int chunk = (NN + 1023) / 1024;      // 49
    const int b0 = t * chunk;
    const int b1 = (b0 + chunk < NN) ? b0 + chunk : NN;
    int sum = 0;
    for (int i = b0; i < b1; ++i) sum += counts[i];
    lds[t] = sum;
    __syncthreads();
    // Hillis-Steele inclusive scan over 1024 partials
    for (int off = 1; off < 1024; off <<= 1) {
        int tmp = (t >= off) ? lds[t - off] : 0;
        __syncthreads();
        lds[t] += tmp;
        __syncthreads();
    }
    int run = (t == 0) ? 0 : lds[t - 1];
    for (int i = b0; i < b1; ++i) {
        row_ptr[i] = run;
        run += counts[i];
    }
    if (t == 1023) row_ptr[NN] = lds[1023];    // == EE
}

// ---------------- CSR build: scatter src ids into per-dst lists ----------------
__global__ void scatter_kernel(const int* __restrict__ src, const int* __restrict__ dst,
                               const int* __restrict__ row_ptr, int* __restrict__ cursor,
                               int* __restrict__ sorted_src) {
    int e = blockIdx.x * 256 + threadIdx.x;
    if (e >= EE) return;
    int d = dst[e];
    int pos = atomicAdd(&cursor[d], 1);
    sorted_src[row_ptr[d] + pos] = src[e];
}

// ---------------- K5: per-node gather aggregation (one wave per node) ----------------
// pass 1: denom[h] = sum over edges of exp(leaky(el[s][h]+er[n][h]))
// pass 2: acc = h[n]+bias + sum_e (w/denom) * feat_src[s]; single write to out
__global__ __launch_bounds__(256) void agg_kernel(const int* __restrict__ row_ptr,
                                                  const int* __restrict__ sorted_src,
                                                  const float* __restrict__ el,
                                                  const float* __restrict__ er,
                                                  const float* __restrict__ feat,
                                                  const float* __restrict__ h,
                                                  const float* __restrict__ bias,
                                                  float* __restrict__ out) {
    int node = blockIdx.x * 4 + (threadIdx.x >> 6);
    if (node >= NN) return;
    int lane = threadIdx.x & 63;
    int beg = row_ptr[node], end = row_ptr[node + 1];
    int g = end - beg;

    // ---- pass 1: denom for head (lane&3); 16 edge-slots in parallel
    int h1 = lane & 3, slot = lane >> 2;
    float er1 = er[node * 4 + h1];
    float p = 0.f;
    for (int j = slot; j < g; j += 16) {
        int s = sorted_src[beg + j];
        float v = el[s * 4 + h1] + er1;
        v = (v > 0.f) ? v : SLOPE * v;
        p += __expf(v);
    }
#pragma unroll
    for (int off = 4; off < 64; off <<= 1) p += __shfl_xor(p, off, 64);
    // every lane now holds denom for head (lane&3)

    // ---- pass 2: lane covers channels 4*lane..4*lane+3, head = lane>>4
    int h2 = lane >> 4;
    float inv_denom = 1.f / __shfl(p, h2, 64);     // lane h2 holds denom of head h2
    float er2 = er[node * 4 + h2];

    float4 acc = ((const float4*)(h + (size_t)node * 256))[lane];
    float4 bv = ((const float4*)bias)[lane];
    acc.x += bv.x; acc.y += bv.y; acc.z += bv.z; acc.w += bv.w;

    for (int j = 0; j < g; ++j) {
        int s = sorted_src[beg + j];               // wave-broadcast load
        float v = el[s * 4 + h2] + er2;
        v = (v > 0.f) ? v : SLOPE * v;
        float c = __expf(v) * inv_denom;
        float4 f = ((const float4*)(feat + (size_t)s * 512))[lane];
        acc.x = fmaf(c, f.x, acc.x);
        acc.y = fmaf(c, f.y, acc.y);
        acc.z = fmaf(c, f.z, acc.z);
        acc.w = fmaf(c, f.w, acc.w);
    }
    ((float4*)(out + (size_t)node * 256))[lane] = acc;
}

extern "C" void kernel_launch(void* const* d_in, const int* in_sizes, int n_in,
                              void* d_out, int out_size, void* d_ws, size_t ws_size,
                              hipStream_t stream) {
    const float* x        = (const float*)d_in[0];
    const int*   eidx     = (const int*)d_in[1];
    const float* mask     = (const float*)d_in[2];
    const float* gamma    = (const float*)d_in[3];
    const float* beta     = (const float*)d_in[4];
    const float* mean     = (const float*)d_in[5];
    const float* var      = (const float*)d_in[6];
    const float* fc_w     = (const float*)d_in[7];
    const float* fc_dst_w = (const float*)d_in[8];
    const float* attn_l   = (const float*)d_in[9];
    const float* attn_r   = (const float*)d_in[10];
    const float* bias     = (const float*)d_in[11];
    float* out = (float*)d_out;

    const int* src = eidx;
    const int* dst = eidx + EE;

    float* ws_f  = (float*)d_ws;
    float* h     = ws_f;                         // N*256
    float* feat  = h + (size_t)NN * 256;         // N*512
    float* el    = feat + (size_t)NN * 512;      // N*4
    float* er    = el + (size_t)NN * 4;          // N*4
    int* counts     = (int*)(er + (size_t)NN * 4);  // N
    int* cursor     = counts + NN;               // N
    int* row_ptr    = cursor + NN;               // N+1
    int* sorted_src = row_ptr + NN + 1;          // E

    // K1: h
    bn_relu_kernel<<<(NN * CC / 4 + 255) / 256, 256, 0, stream>>>(
        x, mask, gamma, beta, mean, var, h);

    // K2: feat = h @ [fc_w | fc_dst_w]^T
    dim3 ggrid((NN + 63) / 64, 8);
    gemm_kernel<<<ggrid, 256, 0, stream>>>(h, fc_w, fc_dst_w, feat);

    // K3: el/er
    elr_kernel<<<NN, 256, 0, stream>>>(feat, attn_l, attn_r, el, er);

    // CSR build
    hipMemsetAsync(counts, 0, 2 * (size_t)NN * sizeof(int), stream);   // counts + cursor
    count_kernel<<<EE / 256, 256, 0, stream>>>(dst, counts);
    scan_kernel<<<1, 1024, 0, stream>>>(counts, row_ptr);
    scatter_kernel<<<EE / 256, 256, 0, stream>>>(src, dst, row_ptr, cursor, sorted_src);

    // K5: gather aggregation, fused residual + bias, single write per output
    agg_kernel<<<(NN + 3) / 4, 256, 0, stream>>>(row_ptr, sorted_src, el, er, feat, h, bias, out);
}

// Round 3
// 382.934 us; speedup vs baseline: 2.8032x; 1.4500x over previous
//
#include <hip/hip_runtime.h>
#include <math.h>

#define NN 50000
#define CC 256
#define HH 4
#define DD 64
#define EE 800000
#define EPS 1e-5f
#define SLOPE 0.2f

typedef __attribute__((ext_vector_type(8))) short bf16x8;
typedef __attribute__((ext_vector_type(4))) float f32x4;

__device__ __forceinline__ unsigned short f2bf(float f) {
    unsigned int u = __float_as_uint(f);
    u += 0x7fffu + ((u >> 16) & 1u);          // RNE
    return (unsigned short)(u >> 16);
}

// ---------------- K1: BN -> ReLU -> mask -> h (fp32) + h_bf16 ----------------
__global__ void bn_relu_kernel(const float* __restrict__ x, const float* __restrict__ mask,
                               const float* __restrict__ gamma, const float* __restrict__ beta,
                               const float* __restrict__ mean, const float* __restrict__ var,
                               float* __restrict__ h, unsigned short* __restrict__ h_bf) {
    int i = blockIdx.x * 256 + threadIdx.x;          // index into N*C/4 float4s
    const int total = NN * CC / 4;
    if (i >= total) return;
    float4 xv = ((const float4*)x)[i];
    float4 mv = ((const float4*)mask)[i];
    int c0 = (i & (CC / 4 - 1)) * 4;
    float4 hv;
    {
        float s = gamma[c0 + 0] * rsqrtf(var[c0 + 0] + EPS);
        float v = (xv.x - mean[c0 + 0]) * s + beta[c0 + 0];
        hv.x = fmaxf(v, 0.f) * mv.x;
    }
    {
        float s = gamma[c0 + 1] * rsqrtf(var[c0 + 1] + EPS);
        float v = (xv.y - mean[c0 + 1]) * s + beta[c0 + 1];
        hv.y = fmaxf(v, 0.f) * mv.y;
    }
    {
        float s = gamma[c0 + 2] * rsqrtf(var[c0 + 2] + EPS);
        float v = (xv.z - mean[c0 + 2]) * s + beta[c0 + 2];
        hv.z = fmaxf(v, 0.f) * mv.z;
    }
    {
        float s = gamma[c0 + 3] * rsqrtf(var[c0 + 3] + EPS);
        float v = (xv.w - mean[c0 + 3]) * s + beta[c0 + 3];
        hv.w = fmaxf(v, 0.f) * mv.w;
    }
    ((float4*)h)[i] = hv;
    ushort4 hb;
    hb.x = f2bf(hv.x); hb.y = f2bf(hv.y); hb.z = f2bf(hv.z); hb.w = f2bf(hv.w);
    ((ushort4*)h_bf)[i] = hb;
}

// ---------------- W conversion: wcat[512][256] bf16 = [fc_w ; fc_dst_w] ----------------
__global__ void wconv_kernel(const float* __restrict__ fc_w, const float* __restrict__ fc_dst_w,
                             unsigned short* __restrict__ wcat) {
    int i = blockIdx.x * 256 + threadIdx.x;          // float4 index, total 32768
    float4 v = (i < 16384) ? ((const float4*)fc_w)[i] : ((const float4*)fc_dst_w)[i - 16384];
    ushort4 o;
    o.x = f2bf(v.x); o.y = f2bf(v.y); o.z = f2bf(v.z); o.w = f2bf(v.w);
    ((ushort4*)wcat)[i] = o;
}

// ---------------- K2: feat[N,512](bf16) = h_bf @ wcat^T via MFMA ----------------
// Block 256 thr = 4 waves (2x2), tile 128x128; wave 64x64 = 4x4 16x16 frags.
// Fragments loaded straight from global (16B/lane); weights L2-resident.
__global__ __launch_bounds__(256) void gemm_mfma_kernel(const unsigned short* __restrict__ A,
                                                        const unsigned short* __restrict__ B,
                                                        unsigned short* __restrict__ feat) {
    const int wave = threadIdx.x >> 6;
    const int lane = threadIdx.x & 63;
    const int wm = wave >> 1, wn = wave & 1;
    const int m0 = blockIdx.x * 128 + wm * 64;
    const int n0 = blockIdx.y * 128 + wn * 64;
    const int lr = lane & 15;                 // row (A) / col (B) within fragment
    const int lk = (lane >> 4) * 8;           // k slot base

    f32x4 acc[4][4] = {};
    const unsigned short* Ab = A + (size_t)(m0 + lr) * 256 + lk;
    const unsigned short* Bb = B + (size_t)(n0 + lr) * 256 + lk;

#pragma unroll
    for (int ks = 0; ks < 8; ++ks) {          // K = 256, BK = 32
        bf16x8 a[4], b[4];
#pragma unroll
        for (int i = 0; i < 4; ++i)
            a[i] = *(const bf16x8*)(Ab + (size_t)i * 16 * 256 + ks * 32);
#pragma unroll
        for (int j = 0; j < 4; ++j)
            b[j] = *(const bf16x8*)(Bb + (size_t)j * 16 * 256 + ks * 32);
#pragma unroll
        for (int i = 0; i < 4; ++i)
#pragma unroll
            for (int j = 0; j < 4; ++j)
                acc[i][j] = __builtin_amdgcn_mfma_f32_16x16x32_bf16(a[i], b[j], acc[i][j], 0, 0, 0);
    }

    const int orow = (lane >> 4) * 4;         // C/D: col = lane&15, row = (lane>>4)*4 + reg
#pragma unroll
    for (int i = 0; i < 4; ++i) {
#pragma unroll
        for (int r = 0; r < 4; ++r) {
            int gr = m0 + i * 16 + orow + r;
            if (gr < NN) {
#pragma unroll
                for (int j = 0; j < 4; ++j)
                    feat[(size_t)gr * 512 + n0 + j * 16 + lr] = f2bf(acc[i][j][r]);
            }
        }
    }
}

// ---------------- K3: el/er from bf16 feat ----------------
__global__ void elr_kernel(const unsigned short* __restrict__ feat,
                           const float* __restrict__ attn_l, const float* __restrict__ attn_r,
                           float* __restrict__ el, float* __restrict__ er) {
    int n = blockIdx.x;
    int t = threadIdx.x;                      // covers cols 2t, 2t+1
    unsigned int v = ((const unsigned int*)(feat + (size_t)n * 512))[t];
    float f0 = __uint_as_float(v << 16);
    float f1 = __uint_as_float(v & 0xffff0000u);
    int col = 2 * t;
    float c0, c1;
    if (col < 256) { c0 = attn_l[col]; c1 = attn_l[col + 1]; }
    else           { c0 = attn_r[col - 256]; c1 = attn_r[col - 255]; }
    float p = f0 * c0 + f1 * c1;
#pragma unroll
    for (int off = 16; off; off >>= 1) p += __shfl_xor(p, off, 32);
    if ((t & 31) == 0) {
        int hh = t >> 5;                      // 0..7
        if (hh < 4) el[n * 4 + hh] = p;
        else        er[n * 4 + (hh - 4)] = p;
    }
}

// ---------------- CSR build ----------------
__global__ void count_kernel(const int* __restrict__ dst, int* __restrict__ counts) {
    int e = blockIdx.x * 256 + threadIdx.x;
    if (e >= EE) return;
    atomicAdd(&counts[dst[e]], 1);
}

__global__ __launch_bounds__(1024) void scan_kernel(const int* __restrict__ counts,
                                                    int* __restrict__ row_ptr) {
    __shared__ int lds[1024];
    const int t = threadIdx.x;
    const int chunk = (NN + 1023) / 1024;
    const int b0 = t * chunk;
    const int b1 = (b0 + chunk < NN) ? b0 + chunk : NN;
    int sum = 0;
    for (int i = b0; i < b1; ++i) sum += counts[i];
    lds[t] = sum;
    __syncthreads();
    for (int off = 1; off < 1024; off <<= 1) {
        int tmp = (t >= off) ? lds[t - off] : 0;
        __syncthreads();
        lds[t] += tmp;
        __syncthreads();
    }
    int run = (t == 0) ? 0 : lds[t - 1];
    for (int i = b0; i < b1; ++i) {
        row_ptr[i] = run;
        run += counts[i];
    }
    if (t == 1023) row_ptr[NN] = lds[1023];
}

__global__ void scatter_kernel(const int* __restrict__ src, const int* __restrict__ dst,
                               const int* __restrict__ row_ptr, int* __restrict__ cursor,
                               int* __restrict__ sorted_src) {
    int e = blockIdx.x * 256 + threadIdx.x;
    if (e >= EE) return;
    int d = dst[e];
    int pos = atomicAdd(&cursor[d], 1);
    sorted_src[row_ptr[d] + pos] = src[e];
}

// ---------------- K5: per-node gather aggregation (one wave per node) ----------------
__global__ __launch_bounds__(256) void agg_kernel(const int* __restrict__ row_ptr,
                                                  const int* __restrict__ sorted_src,
                                                  const float* __restrict__ el,
                                                  const float* __restrict__ er,
                                                  const unsigned short* __restrict__ feat,
                                                  const float* __restrict__ h,
                                                  const float* __restrict__ bias,
                                                  float* __restrict__ out) {
    int node = blockIdx.x * 4 + (threadIdx.x >> 6);
    if (node >= NN) return;
    int lane = threadIdx.x & 63;
    int beg = row_ptr[node], end = row_ptr[node + 1];
    int g = end - beg;

    // pass 1: denom for head (lane&3), 16 edge-slots parallel
    int h1 = lane & 3, slot = lane >> 2;
    float er1 = er[node * 4 + h1];
    float p = 0.f;
    for (int j = slot; j < g; j += 16) {
        int s = sorted_src[beg + j];
        float v = el[s * 4 + h1] + er1;
        v = (v > 0.f) ? v : SLOPE * v;
        p += __expf(v);
    }
#pragma unroll
    for (int off = 4; off < 64; off <<= 1) p += __shfl_xor(p, off, 64);

    // pass 2: lane covers channels 4*lane..4*lane+3, head = lane>>4
    int h2 = lane >> 4;
    float inv_denom = 1.f / __shfl(p, h2, 64);
    float er2 = er[node * 4 + h2];

    float4 acc = ((const float4*)(h + (size_t)node * 256))[lane];
    float4 bv = ((const float4*)bias)[lane];
    acc.x += bv.x; acc.y += bv.y; acc.z += bv.z; acc.w += bv.w;

    for (int j = 0; j < g; ++j) {
        int s = sorted_src[beg + j];          // wave-broadcast
        float v = el[s * 4 + h2] + er2;
        v = (v > 0.f) ? v : SLOPE * v;
        float c = __expf(v) * inv_denom;
        uint2 q = ((const uint2*)(feat + (size_t)s * 512))[lane];   // src half: shorts 4l..4l+3
        acc.x = fmaf(c, __uint_as_float(q.x << 16), acc.x);
        acc.y = fmaf(c, __uint_as_float(q.x & 0xffff0000u), acc.y);
        acc.z = fmaf(c, __uint_as_float(q.y << 16), acc.z);
        acc.w = fmaf(c, __uint_as_float(q.y & 0xffff0000u), acc.w);
    }
    ((float4*)(out + (size_t)node * 256))[lane] = acc;
}

extern "C" void kernel_launch(void* const* d_in, const int* in_sizes, int n_in,
                              void* d_out, int out_size, void* d_ws, size_t ws_size,
                              hipStream_t stream) {
    const float* x        = (const float*)d_in[0];
    const int*   eidx     = (const int*)d_in[1];
    const float* mask     = (const float*)d_in[2];
    const float* gamma    = (const float*)d_in[3];
    const float* beta     = (const float*)d_in[4];
    const float* mean     = (const float*)d_in[5];
    const float* var      = (const float*)d_in[6];
    const float* fc_w     = (const float*)d_in[7];
    const float* fc_dst_w = (const float*)d_in[8];
    const float* attn_l   = (const float*)d_in[9];
    const float* attn_r   = (const float*)d_in[10];
    const float* bias     = (const float*)d_in[11];
    float* out = (float*)d_out;

    const int* src = eidx;
    const int* dst = eidx + EE;

    const size_t NPAD = 50048;                 // 391*128 rows, GEMM tail reads stay in ws
    float* h             = (float*)d_ws;                          // N*256 f32
    unsigned short* h_bf = (unsigned short*)(h + (size_t)NN * 256);   // NPAD*256 bf16
    unsigned short* wcat = h_bf + NPAD * 256;                     // 512*256 bf16
    unsigned short* feat = wcat + 512 * 256;                      // NPAD*512 bf16
    float* el            = (float*)(feat + NPAD * 512);           // N*4
    float* er            = el + (size_t)NN * 4;                   // N*4
    int* counts          = (int*)(er + (size_t)NN * 4);           // N
    int* cursor          = counts + NN;                           // N
    int* row_ptr         = cursor + NN;                           // N+1
    int* sorted_src      = row_ptr + NN + 1;                      // E

    bn_relu_kernel<<<(NN * CC / 4 + 255) / 256, 256, 0, stream>>>(
        x, mask, gamma, beta, mean, var, h, h_bf);

    wconv_kernel<<<128, 256, 0, stream>>>(fc_w, fc_dst_w, wcat);

    dim3 ggrid((NN + 127) / 128, 4);
    gemm_mfma_kernel<<<ggrid, 256, 0, stream>>>(h_bf, wcat, feat);

    elr_kernel<<<NN, 256, 0, stream>>>(feat, attn_l, attn_r, el, er);

    hipMemsetAsync(counts, 0, 2 * (size_t)NN * sizeof(int), stream);
    count_kernel<<<EE / 256, 256, 0, stream>>>(dst, counts);
    scan_kernel<<<1, 1024, 0, stream>>>(counts, row_ptr);
    scatter_kernel<<<EE / 256, 256, 0, stream>>>(src, dst, row_ptr, cursor, sorted_src);

    agg_kernel<<<(NN + 3) / 4, 256, 0, stream>>>(row_ptr, sorted_src, el, er, feat, h, bias, out);
}

// Round 4
// 313.713 us; speedup vs baseline: 3.4217x; 1.2207x over previous
//
#include <hip/hip_runtime.h>
#include <math.h>

#define NN 50000
#define CC 256
#define HH 4
#define DD 64
#define EE 800000
#define EPS 1e-5f
#define SLOPE 0.2f

typedef __attribute__((ext_vector_type(8))) short bf16x8;
typedef __attribute__((ext_vector_type(4))) float f32x4;

__device__ __forceinline__ unsigned short f2bf(float f) {
    unsigned int u = __float_as_uint(f);
    u += 0x7fffu + ((u >> 16) & 1u);          // RNE
    return (unsigned short)(u >> 16);
}
__device__ __forceinline__ float bflo(unsigned int u) { return __uint_as_float(u << 16); }
__device__ __forceinline__ float bfhi(unsigned int u) { return __uint_as_float(u & 0xffff0000u); }

// ---------------- K1: BN -> ReLU -> mask -> h_bf16; also count dst histogram ----------------
__global__ void bn_relu_kernel(const float* __restrict__ x, const float* __restrict__ mask,
                               const float* __restrict__ gamma, const float* __restrict__ beta,
                               const float* __restrict__ mean, const float* __restrict__ var,
                               const int* __restrict__ dst, unsigned short* __restrict__ h_bf,
                               int* __restrict__ counts) {
    int i = blockIdx.x * 256 + threadIdx.x;          // float4 index, N*C/4 total
    const int total = NN * CC / 4;
    if (i >= total) return;
    float4 xv = ((const float4*)x)[i];
    float4 mv = ((const float4*)mask)[i];
    int c0 = (i & (CC / 4 - 1)) * 4;
    float4 hv;
    {
        float s = gamma[c0 + 0] * rsqrtf(var[c0 + 0] + EPS);
        float v = (xv.x - mean[c0 + 0]) * s + beta[c0 + 0];
        hv.x = fmaxf(v, 0.f) * mv.x;
    }
    {
        float s = gamma[c0 + 1] * rsqrtf(var[c0 + 1] + EPS);
        float v = (xv.y - mean[c0 + 1]) * s + beta[c0 + 1];
        hv.y = fmaxf(v, 0.f) * mv.y;
    }
    {
        float s = gamma[c0 + 2] * rsqrtf(var[c0 + 2] + EPS);
        float v = (xv.z - mean[c0 + 2]) * s + beta[c0 + 2];
        hv.z = fmaxf(v, 0.f) * mv.z;
    }
    {
        float s = gamma[c0 + 3] * rsqrtf(var[c0 + 3] + EPS);
        float v = (xv.w - mean[c0 + 3]) * s + beta[c0 + 3];
        hv.w = fmaxf(v, 0.f) * mv.w;
    }
    ushort4 hb;
    hb.x = f2bf(hv.x); hb.y = f2bf(hv.y); hb.z = f2bf(hv.z); hb.w = f2bf(hv.w);
    ((ushort4*)h_bf)[i] = hb;
    if (i < EE) atomicAdd(&counts[dst[i]], 1);       // fused CSR histogram
}

// ---------------- W conversion ----------------
__global__ void wconv_kernel(const float* __restrict__ fc_w, const float* __restrict__ fc_dst_w,
                             unsigned short* __restrict__ wcat) {
    int i = blockIdx.x * 256 + threadIdx.x;
    float4 v = (i < 16384) ? ((const float4*)fc_w)[i] : ((const float4*)fc_dst_w)[i - 16384];
    ushort4 o;
    o.x = f2bf(v.x); o.y = f2bf(v.y); o.z = f2bf(v.z); o.w = f2bf(v.w);
    ((ushort4*)wcat)[i] = o;
}

// ---------------- K2: feat = h_bf @ wcat^T (MFMA) + fused el/er epilogue ----------------
// 512 thr = 8 waves (2x4); block tile 128x256; wave 64x64. Each wave's 64 cols = one head.
__global__ __launch_bounds__(512) void gemm_mfma_kernel(const unsigned short* __restrict__ A,
                                                        const unsigned short* __restrict__ B,
                                                        const float* __restrict__ attn_l,
                                                        const float* __restrict__ attn_r,
                                                        unsigned short* __restrict__ feat,
                                                        float* __restrict__ el,
                                                        float* __restrict__ er) {
    const int wave = threadIdx.x >> 6;
    const int lane = threadIdx.x & 63;
    const int wm = wave >> 2, wn = wave & 3;
    const int m0 = blockIdx.x * 128 + wm * 64;
    const int n0 = blockIdx.y * 256 + wn * 64;
    const int lr = lane & 15;
    const int lk = (lane >> 4) * 8;

    f32x4 acc[4][4] = {};
    const unsigned short* Ab = A + (size_t)(m0 + lr) * 256 + lk;
    const unsigned short* Bb = B + (size_t)(n0 + lr) * 256 + lk;

#pragma unroll
    for (int ks = 0; ks < 8; ++ks) {          // K = 256, BK = 32
        bf16x8 a[4], b[4];
#pragma unroll
        for (int i = 0; i < 4; ++i)
            a[i] = *(const bf16x8*)(Ab + (size_t)i * 16 * 256 + ks * 32);
#pragma unroll
        for (int j = 0; j < 4; ++j)
            b[j] = *(const bf16x8*)(Bb + (size_t)j * 16 * 256 + ks * 32);
#pragma unroll
        for (int i = 0; i < 4; ++i)
#pragma unroll
            for (int j = 0; j < 4; ++j)
                acc[i][j] = __builtin_amdgcn_mfma_f32_16x16x32_bf16(a[i], b[j], acc[i][j], 0, 0, 0);
    }

    const int orow = (lane >> 4) * 4;         // C/D: col = lane&15, row = (lane>>4)*4 + reg
#pragma unroll
    for (int i = 0; i < 4; ++i) {
#pragma unroll
        for (int r = 0; r < 4; ++r) {
            int gr = m0 + i * 16 + orow + r;
            if (gr < NN) {
#pragma unroll
                for (int j = 0; j < 4; ++j)
                    feat[(size_t)gr * 512 + n0 + j * 16 + lr] = f2bf(acc[i][j][r]);
            }
        }
    }

    // ---- fused el/er: this wave's 64 cols = head (cb&3) of attn_l (cb<4) or attn_r ----
    const int cb = n0 >> 6;                   // 0..7
    const float* attn = (cb < 4) ? attn_l : attn_r;
    float* ep = (cb < 4) ? el : er;
    const int head = cb & 3;
    float coef[4];
#pragma unroll
    for (int j = 0; j < 4; ++j) coef[j] = attn[head * 64 + j * 16 + lr];

    float pv[16];
#pragma unroll
    for (int i = 0; i < 4; ++i)
#pragma unroll
        for (int r = 0; r < 4; ++r)
            pv[i * 4 + r] = acc[i][0][r] * coef[0] + acc[i][1][r] * coef[1] +
                            acc[i][2][r] * coef[2] + acc[i][3][r] * coef[3];
#pragma unroll
    for (int msk = 1; msk < 16; msk <<= 1)
#pragma unroll
        for (int k = 0; k < 16; ++k)
            pv[k] += __shfl_xor(pv[k], msk, 64);
    // lane lr stores (i=lr>>2, r=lr&3); compile-time select to avoid scratch
    float sel = pv[0];
#pragma unroll
    for (int k = 1; k < 16; ++k)
        if (lr == k) sel = pv[k];
    int gr = m0 + (lr >> 2) * 16 + orow + (lr & 3);
    if (gr < NN) ep[gr * 4 + head] = sel;
}

// ---------------- CSR: single-block exclusive scan ----------------
__global__ __launch_bounds__(1024) void scan_kernel(const int* __restrict__ counts,
                                                    int* __restrict__ row_ptr) {
    __shared__ int lds[1024];
    const int t = threadIdx.x;
    const int chunk = (NN + 1023) / 1024;
    const int b0 = t * chunk;
    const int b1 = (b0 + chunk < NN) ? b0 + chunk : NN;
    int sum = 0;
    for (int i = b0; i < b1; ++i) sum += counts[i];
    lds[t] = sum;
    __syncthreads();
    for (int off = 1; off < 1024; off <<= 1) {
        int tmp = (t >= off) ? lds[t - off] : 0;
        __syncthreads();
        lds[t] += tmp;
        __syncthreads();
    }
    int run = (t == 0) ? 0 : lds[t - 1];
    for (int i = b0; i < b1; ++i) {
        row_ptr[i] = run;
        run += counts[i];
    }
    if (t == 1023) row_ptr[NN] = lds[1023];
}

// ---------------- CSR: scatter src ids ----------------
__global__ void scatter_kernel(const int* __restrict__ src, const int* __restrict__ dst,
                               const int* __restrict__ row_ptr, int* __restrict__ cursor,
                               int* __restrict__ sorted_src) {
    int e = blockIdx.x * 256 + threadIdx.x;
    if (e >= EE) return;
    int d = dst[e];
    int pos = atomicAdd(&cursor[d], 1);
    sorted_src[row_ptr[d] + pos] = src[e];
}

// ---------------- K5: single-pass gather agg, 4-wide pipelined ----------------
// out[n] = h_bf[n] + bias + (Σ_e w_e * feat_src[e]) / (Σ_e w_e)
__global__ __launch_bounds__(256) void agg_kernel(const int* __restrict__ row_ptr,
                                                  const int* __restrict__ sorted_src,
                                                  const float* __restrict__ el,
                                                  const float* __restrict__ er,
                                                  const unsigned short* __restrict__ feat,
                                                  const unsigned short* __restrict__ h_bf,
                                                  const float* __restrict__ bias,
                                                  float* __restrict__ out) {
    int node = blockIdx.x * 4 + (threadIdx.x >> 6);
    if (node >= NN) return;
    int lane = threadIdx.x & 63;
    int beg = row_ptr[node];
    int g = row_ptr[node + 1] - beg;
    int h2 = lane >> 4;                        // head of channels 4*lane..4*lane+3
    float er2 = er[node * 4 + h2];
    const int* ss = sorted_src + beg;

    float den = 0.f;
    float a0 = 0.f, a1 = 0.f, a2 = 0.f, a3 = 0.f;
    int j = 0;
    for (; j + 4 <= g; j += 4) {
        int s0 = ss[j], s1 = ss[j + 1], s2 = ss[j + 2], s3 = ss[j + 3];
        float v0 = el[s0 * 4 + h2] + er2;
        float v1 = el[s1 * 4 + h2] + er2;
        float v2 = el[s2 * 4 + h2] + er2;
        float v3 = el[s3 * 4 + h2] + er2;
        uint2 q0 = ((const uint2*)(feat + (size_t)s0 * 512))[lane];
        uint2 q1 = ((const uint2*)(feat + (size_t)s1 * 512))[lane];
        uint2 q2 = ((const uint2*)(feat + (size_t)s2 * 512))[lane];
        uint2 q3 = ((const uint2*)(feat + (size_t)s3 * 512))[lane];
        v0 = (v0 > 0.f) ? v0 : SLOPE * v0; float c0 = __expf(v0);
        v1 = (v1 > 0.f) ? v1 : SLOPE * v1; float c1 = __expf(v1);
        v2 = (v2 > 0.f) ? v2 : SLOPE * v2; float c2 = __expf(v2);
        v3 = (v3 > 0.f) ? v3 : SLOPE * v3; float c3 = __expf(v3);
        den += (c0 + c1) + (c2 + c3);
        a0 = fmaf(c0, bflo(q0.x), a0); a1 = fmaf(c0, bfhi(q0.x), a1);
        a2 = fmaf(c0, bflo(q0.y), a2); a3 = fmaf(c0, bfhi(q0.y), a3);
        a0 = fmaf(c1, bflo(q1.x), a0); a1 = fmaf(c1, bfhi(q1.x), a1);
        a2 = fmaf(c1, bflo(q1.y), a2); a3 = fmaf(c1, bfhi(q1.y), a3);
        a0 = fmaf(c2, bflo(q2.x), a0); a1 = fmaf(c2, bfhi(q2.x), a1);
        a2 = fmaf(c2, bflo(q2.y), a2); a3 = fmaf(c2, bfhi(q2.y), a3);
        a0 = fmaf(c3, bflo(q3.x), a0); a1 = fmaf(c3, bfhi(q3.x), a1);
        a2 = fmaf(c3, bflo(q3.y), a2); a3 = fmaf(c3, bfhi(q3.y), a3);
    }
    for (; j < g; ++j) {
        int s = ss[j];
        float v = el[s * 4 + h2] + er2;
        uint2 q = ((const uint2*)(feat + (size_t)s * 512))[lane];
        v = (v > 0.f) ? v : SLOPE * v;
        float c = __expf(v);
        den += c;
        a0 = fmaf(c, bflo(q.x), a0); a1 = fmaf(c, bfhi(q.x), a1);
        a2 = fmaf(c, bflo(q.y), a2); a3 = fmaf(c, bfhi(q.y), a3);
    }
    float inv = (g > 0) ? 1.f / den : 0.f;

    uint2 hb = ((const uint2*)(h_bf + (size_t)node * 256))[lane];
    float4 bv = ((const float4*)bias)[lane];
    float4 o;
    o.x = bflo(hb.x) + bv.x + a0 * inv;
    o.y = bfhi(hb.x) + bv.y + a1 * inv;
    o.z = bflo(hb.y) + bv.z + a2 * inv;
    o.w = bfhi(hb.y) + bv.w + a3 * inv;
    ((float4*)(out + (size_t)node * 256))[lane] = o;
}

extern "C" void kernel_launch(void* const* d_in, const int* in_sizes, int n_in,
                              void* d_out, int out_size, void* d_ws, size_t ws_size,
                              hipStream_t stream) {
    const float* x        = (const float*)d_in[0];
    const int*   eidx     = (const int*)d_in[1];
    const float* mask     = (const float*)d_in[2];
    const float* gamma    = (const float*)d_in[3];
    const float* beta     = (const float*)d_in[4];
    const float* mean     = (const float*)d_in[5];
    const float* var      = (const float*)d_in[6];
    const float* fc_w     = (const float*)d_in[7];
    const float* fc_dst_w = (const float*)d_in[8];
    const float* attn_l   = (const float*)d_in[9];
    const float* attn_r   = (const float*)d_in[10];
    const float* bias     = (const float*)d_in[11];
    float* out = (float*)d_out;

    const int* src = eidx;
    const int* dst = eidx + EE;

    const size_t NPAD = 50048;                 // 391*128 rows
    unsigned short* h_bf = (unsigned short*)d_ws;                 // NPAD*256 bf16
    unsigned short* wcat = h_bf + NPAD * 256;                     // 512*256 bf16
    unsigned short* feat = wcat + 512 * 256;                      // NPAD*512 bf16
    float* el            = (float*)(feat + NPAD * 512);           // N*4
    float* er            = el + (size_t)NN * 4;                   // N*4
    int* counts          = (int*)(er + (size_t)NN * 4);           // N
    int* cursor          = counts + NN;                           // N
    int* row_ptr         = cursor + NN;                           // N+1
    int* sorted_src      = row_ptr + NN + 1;                      // E

    hipMemsetAsync(counts, 0, 2 * (size_t)NN * sizeof(int), stream);   // counts + cursor

    bn_relu_kernel<<<(NN * CC / 4 + 255) / 256, 256, 0, stream>>>(
        x, mask, gamma, beta, mean, var, dst, h_bf, counts);

    wconv_kernel<<<128, 256, 0, stream>>>(fc_w, fc_dst_w, wcat);

    scan_kernel<<<1, 1024, 0, stream>>>(counts, row_ptr);

    dim3 ggrid((NN + 127) / 128, 2);
    gemm_mfma_kernel<<<ggrid, 512, 0, stream>>>(h_bf, wcat, attn_l, attn_r, feat, el, er);

    scatter_kernel<<<(EE + 255) / 256, 256, 0, stream>>>(src, dst, row_ptr, cursor, sorted_src);

    agg_kernel<<<(NN + 3) / 4, 256, 0, stream>>>(row_ptr, sorted_src, el, er, feat, h_bf, bias, out);
}

// Round 5
// 214.101 us; speedup vs baseline: 5.0136x; 1.4653x over previous
//
#include <hip/hip_runtime.h>
#include <math.h>

#define NN 50000
#define CC 256
#define HH 4
#define DD 64
#define EE 800000
#define EPS 1e-5f
#define SLOPE 0.2f
#define SCAN_NBLK ((NN + 1023) / 1024)   // 49

typedef __attribute__((ext_vector_type(8))) short bf16x8;
typedef __attribute__((ext_vector_type(4))) float f32x4;

__device__ __forceinline__ unsigned short f2bf(float f) {
    unsigned int u = __float_as_uint(f);
    u += 0x7fffu + ((u >> 16) & 1u);          // RNE
    return (unsigned short)(u >> 16);
}
__device__ __forceinline__ float bflo(unsigned int u) { return __uint_as_float(u << 16); }
__device__ __forceinline__ float bfhi(unsigned int u) { return __uint_as_float(u & 0xffff0000u); }

// ---------------- K1: BN -> ReLU -> mask -> h_bf16; fused dst histogram + edge pos ----------------
__global__ void bn_relu_kernel(const float* __restrict__ x, const float* __restrict__ mask,
                               const float* __restrict__ gamma, const float* __restrict__ beta,
                               const float* __restrict__ mean, const float* __restrict__ var,
                               const int* __restrict__ dst, unsigned short* __restrict__ h_bf,
                               int* __restrict__ counts, int* __restrict__ epos) {
    int i = blockIdx.x * 256 + threadIdx.x;          // float4 index, N*C/4 total
    const int total = NN * CC / 4;
    if (i >= total) return;
    float4 xv = ((const float4*)x)[i];
    float4 mv = ((const float4*)mask)[i];
    int c0 = (i & (CC / 4 - 1)) * 4;
    float4 hv;
    {
        float s = gamma[c0 + 0] * rsqrtf(var[c0 + 0] + EPS);
        float v = (xv.x - mean[c0 + 0]) * s + beta[c0 + 0];
        hv.x = fmaxf(v, 0.f) * mv.x;
    }
    {
        float s = gamma[c0 + 1] * rsqrtf(var[c0 + 1] + EPS);
        float v = (xv.y - mean[c0 + 1]) * s + beta[c0 + 1];
        hv.y = fmaxf(v, 0.f) * mv.y;
    }
    {
        float s = gamma[c0 + 2] * rsqrtf(var[c0 + 2] + EPS);
        float v = (xv.z - mean[c0 + 2]) * s + beta[c0 + 2];
        hv.z = fmaxf(v, 0.f) * mv.z;
    }
    {
        float s = gamma[c0 + 3] * rsqrtf(var[c0 + 3] + EPS);
        float v = (xv.w - mean[c0 + 3]) * s + beta[c0 + 3];
        hv.w = fmaxf(v, 0.f) * mv.w;
    }
    ushort4 hb;
    hb.x = f2bf(hv.x); hb.y = f2bf(hv.y); hb.z = f2bf(hv.z); hb.w = f2bf(hv.w);
    ((ushort4*)h_bf)[i] = hb;
    if (i < EE) epos[i] = atomicAdd(&counts[dst[i]], 1);   // histogram + per-edge slot
}

// ---------------- W conversion ----------------
__global__ void wconv_kernel(const float* __restrict__ fc_w, const float* __restrict__ fc_dst_w,
                             unsigned short* __restrict__ wcat) {
    int i = blockIdx.x * 256 + threadIdx.x;
    float4 v = (i < 16384) ? ((const float4*)fc_w)[i] : ((const float4*)fc_dst_w)[i - 16384];
    ushort4 o;
    o.x = f2bf(v.x); o.y = f2bf(v.y); o.z = f2bf(v.z); o.w = f2bf(v.w);
    ((ushort4*)wcat)[i] = o;
}

// ---------------- K2: feat = h_bf @ wcat^T (MFMA) + fused el/er epilogue ----------------
__global__ __launch_bounds__(512) void gemm_mfma_kernel(const unsigned short* __restrict__ A,
                                                        const unsigned short* __restrict__ B,
                                                        const float* __restrict__ attn_l,
                                                        const float* __restrict__ attn_r,
                                                        unsigned short* __restrict__ feat,
                                                        float* __restrict__ el,
                                                        float* __restrict__ er) {
    const int wave = threadIdx.x >> 6;
    const int lane = threadIdx.x & 63;
    const int wm = wave >> 2, wn = wave & 3;
    const int m0 = blockIdx.x * 128 + wm * 64;
    const int n0 = blockIdx.y * 256 + wn * 64;
    const int lr = lane & 15;
    const int lk = (lane >> 4) * 8;

    f32x4 acc[4][4] = {};
    const unsigned short* Ab = A + (size_t)(m0 + lr) * 256 + lk;
    const unsigned short* Bb = B + (size_t)(n0 + lr) * 256 + lk;

#pragma unroll
    for (int ks = 0; ks < 8; ++ks) {          // K = 256, BK = 32
        bf16x8 a[4], b[4];
#pragma unroll
        for (int i = 0; i < 4; ++i)
            a[i] = *(const bf16x8*)(Ab + (size_t)i * 16 * 256 + ks * 32);
#pragma unroll
        for (int j = 0; j < 4; ++j)
            b[j] = *(const bf16x8*)(Bb + (size_t)j * 16 * 256 + ks * 32);
#pragma unroll
        for (int i = 0; i < 4; ++i)
#pragma unroll
            for (int j = 0; j < 4; ++j)
                acc[i][j] = __builtin_amdgcn_mfma_f32_16x16x32_bf16(a[i], b[j], acc[i][j], 0, 0, 0);
    }

    const int orow = (lane >> 4) * 4;         // C/D: col = lane&15, row = (lane>>4)*4 + reg
#pragma unroll
    for (int i = 0; i < 4; ++i) {
#pragma unroll
        for (int r = 0; r < 4; ++r) {
            int gr = m0 + i * 16 + orow + r;
            if (gr < NN) {
#pragma unroll
                for (int j = 0; j < 4; ++j)
                    feat[(size_t)gr * 512 + n0 + j * 16 + lr] = f2bf(acc[i][j][r]);
            }
        }
    }

    // ---- fused el/er ----
    const int cb = n0 >> 6;                   // 0..7
    const float* attn = (cb < 4) ? attn_l : attn_r;
    float* ep = (cb < 4) ? el : er;
    const int head = cb & 3;
    float coef[4];
#pragma unroll
    for (int j = 0; j < 4; ++j) coef[j] = attn[head * 64 + j * 16 + lr];

    float pv[16];
#pragma unroll
    for (int i = 0; i < 4; ++i)
#pragma unroll
        for (int r = 0; r < 4; ++r)
            pv[i * 4 + r] = acc[i][0][r] * coef[0] + acc[i][1][r] * coef[1] +
                            acc[i][2][r] * coef[2] + acc[i][3][r] * coef[3];
#pragma unroll
    for (int msk = 1; msk < 16; msk <<= 1)
#pragma unroll
        for (int k = 0; k < 16; ++k)
            pv[k] += __shfl_xor(pv[k], msk, 64);
    float sel = pv[0];
#pragma unroll
    for (int k = 1; k < 16; ++k)
        if (lr == k) sel = pv[k];
    int gr = m0 + (lr >> 2) * 16 + orow + (lr & 3);
    if (gr < NN) ep[gr * 4 + head] = sel;
}

// ---------------- Scan phase 1: per-block sums of 1024 counts ----------------
__global__ __launch_bounds__(256) void scan1_kernel(const int* __restrict__ counts,
                                                    int* __restrict__ bsums) {
    __shared__ int lds[256];
    int b = blockIdx.x, t = threadIdx.x;
    int base = b * 1024 + t * 4;
    int s = 0;
    if (base < NN) {
        int4 v = *(const int4*)(counts + base);
        s = v.x + v.y + v.z + v.w;
    }
    lds[t] = s;
    __syncthreads();
#pragma unroll
    for (int off = 128; off; off >>= 1) {
        if (t < off) lds[t] += lds[t + off];
        __syncthreads();
    }
    if (t == 0) bsums[b] = lds[0];
}

// ---------------- Scan phase 2: block offset from bsums + in-block scan -> row_ptr ----------------
__global__ __launch_bounds__(256) void scan2_kernel(const int* __restrict__ counts,
                                                    const int* __restrict__ bsums,
                                                    int* __restrict__ row_ptr) {
    __shared__ int lds[256];
    __shared__ int soff;
    int b = blockIdx.x, t = threadIdx.x;
    if (t < 64) {                              // wave 0: offset = sum bsums[0..b-1]
        int p = (t < b) ? bsums[t] : 0;
#pragma unroll
        for (int off = 32; off; off >>= 1) p += __shfl_down(p, off, 64);
        if (t == 0) soff = p;
    }
    int base = b * 1024 + t * 4;
    int4 v = {0, 0, 0, 0};
    if (base < NN) v = *(const int4*)(counts + base);
    int s = v.x + v.y + v.z + v.w;
    lds[t] = s;
    __syncthreads();
    for (int off = 1; off < 256; off <<= 1) {  // Hillis-Steele inclusive
        int tmp = (t >= off) ? lds[t - off] : 0;
        __syncthreads();
        lds[t] += tmp;
        __syncthreads();
    }
    if (base < NN) {
        int excl = lds[t] - s + soff;
        row_ptr[base] = excl;
        row_ptr[base + 1] = excl + v.x;
        row_ptr[base + 2] = excl + v.x + v.y;
        row_ptr[base + 3] = excl + v.x + v.y + v.z;
    }
    if (b == 0 && t == 0) row_ptr[NN] = EE;
}

// ---------------- Scatter (atomic-free): sorted_src[row_ptr[d] + epos[e]] = src[e] ----------------
__global__ void scatter_kernel(const int* __restrict__ src, const int* __restrict__ dst,
                               const int* __restrict__ row_ptr, const int* __restrict__ epos,
                               int* __restrict__ sorted_src) {
    int e = blockIdx.x * 256 + threadIdx.x;
    if (e >= EE) return;
    sorted_src[row_ptr[dst[e]] + epos[e]] = src[e];
}

// ---------------- K5: single-pass gather agg, 4-wide pipelined ----------------
__global__ __launch_bounds__(256) void agg_kernel(const int* __restrict__ row_ptr,
                                                  const int* __restrict__ sorted_src,
                                                  const float* __restrict__ el,
                                                  const float* __restrict__ er,
                                                  const unsigned short* __restrict__ feat,
                                                  const unsigned short* __restrict__ h_bf,
                                                  const float* __restrict__ bias,
                                                  float* __restrict__ out) {
    int node = blockIdx.x * 4 + (threadIdx.x >> 6);
    if (node >= NN) return;
    int lane = threadIdx.x & 63;
    int beg = row_ptr[node];
    int g = row_ptr[node + 1] - beg;
    int h2 = lane >> 4;
    float er2 = er[node * 4 + h2];
    const int* ss = sorted_src + beg;

    float den = 0.f;
    float a0 = 0.f, a1 = 0.f, a2 = 0.f, a3 = 0.f;
    int j = 0;
    for (; j + 4 <= g; j += 4) {
        int s0 = ss[j], s1 = ss[j + 1], s2 = ss[j + 2], s3 = ss[j + 3];
        float v0 = el[s0 * 4 + h2] + er2;
        float v1 = el[s1 * 4 + h2] + er2;
        float v2 = el[s2 * 4 + h2] + er2;
        float v3 = el[s3 * 4 + h2] + er2;
        uint2 q0 = ((const uint2*)(feat + (size_t)s0 * 512))[lane];
        uint2 q1 = ((const uint2*)(feat + (size_t)s1 * 512))[lane];
        uint2 q2 = ((const uint2*)(feat + (size_t)s2 * 512))[lane];
        uint2 q3 = ((const uint2*)(feat + (size_t)s3 * 512))[lane];
        v0 = (v0 > 0.f) ? v0 : SLOPE * v0; float c0 = __expf(v0);
        v1 = (v1 > 0.f) ? v1 : SLOPE * v1; float c1 = __expf(v1);
        v2 = (v2 > 0.f) ? v2 : SLOPE * v2; float c2 = __expf(v2);
        v3 = (v3 > 0.f) ? v3 : SLOPE * v3; float c3 = __expf(v3);
        den += (c0 + c1) + (c2 + c3);
        a0 = fmaf(c0, bflo(q0.x), a0); a1 = fmaf(c0, bfhi(q0.x), a1);
        a2 = fmaf(c0, bflo(q0.y), a2); a3 = fmaf(c0, bfhi(q0.y), a3);
        a0 = fmaf(c1, bflo(q1.x), a0); a1 = fmaf(c1, bfhi(q1.x), a1);
        a2 = fmaf(c1, bflo(q1.y), a2); a3 = fmaf(c1, bfhi(q1.y), a3);
        a0 = fmaf(c2, bflo(q2.x), a0); a1 = fmaf(c2, bfhi(q2.x), a1);
        a2 = fmaf(c2, bflo(q2.y), a2); a3 = fmaf(c2, bfhi(q2.y), a3);
        a0 = fmaf(c3, bflo(q3.x), a0); a1 = fmaf(c3, bfhi(q3.x), a1);
        a2 = fmaf(c3, bflo(q3.y), a2); a3 = fmaf(c3, bfhi(q3.y), a3);
    }
    for (; j < g; ++j) {
        int s = ss[j];
        float v = el[s * 4 + h2] + er2;
        uint2 q = ((const uint2*)(feat + (size_t)s * 512))[lane];
        v = (v > 0.f) ? v : SLOPE * v;
        float c = __expf(v);
        den += c;
        a0 = fmaf(c, bflo(q.x), a0); a1 = fmaf(c, bfhi(q.x), a1);
        a2 = fmaf(c, bflo(q.y), a2); a3 = fmaf(c, bfhi(q.y), a3);
    }
    float inv = (g > 0) ? 1.f / den : 0.f;

    uint2 hb = ((const uint2*)(h_bf + (size_t)node * 256))[lane];
    float4 bv = ((const float4*)bias)[lane];
    float4 o;
    o.x = bflo(hb.x) + bv.x + a0 * inv;
    o.y = bfhi(hb.x) + bv.y + a1 * inv;
    o.z = bflo(hb.y) + bv.z + a2 * inv;
    o.w = bfhi(hb.y) + bv.w + a3 * inv;
    ((float4*)(out + (size_t)node * 256))[lane] = o;
}

extern "C" void kernel_launch(void* const* d_in, const int* in_sizes, int n_in,
                              void* d_out, int out_size, void* d_ws, size_t ws_size,
                              hipStream_t stream) {
    const float* x        = (const float*)d_in[0];
    const int*   eidx     = (const int*)d_in[1];
    const float* mask     = (const float*)d_in[2];
    const float* gamma    = (const float*)d_in[3];
    const float* beta     = (const float*)d_in[4];
    const float* mean     = (const float*)d_in[5];
    const float* var      = (const float*)d_in[6];
    const float* fc_w     = (const float*)d_in[7];
    const float* fc_dst_w = (const float*)d_in[8];
    const float* attn_l   = (const float*)d_in[9];
    const float* attn_r   = (const float*)d_in[10];
    const float* bias     = (const float*)d_in[11];
    float* out = (float*)d_out;

    const int* src = eidx;
    const int* dst = eidx + EE;

    const size_t NPAD = 50048;                 // 391*128 rows
    unsigned short* h_bf = (unsigned short*)d_ws;                 // NPAD*256 bf16
    unsigned short* wcat = h_bf + NPAD * 256;                     // 512*256 bf16
    unsigned short* feat = wcat + 512 * 256;                      // NPAD*512 bf16
    float* el            = (float*)(feat + NPAD * 512);           // N*4
    float* er            = el + (size_t)NN * 4;                   // N*4
    int* counts          = (int*)(er + (size_t)NN * 4);           // N  (16B-aligned)
    int* row_ptr         = counts + NN;                           // N+1
    int* sorted_src      = row_ptr + NN + 1;                      // E
    int* epos            = sorted_src + EE;                       // E
    int* bsums           = epos + EE;                             // SCAN_NBLK

    hipMemsetAsync(counts, 0, (size_t)NN * sizeof(int), stream);

    bn_relu_kernel<<<(NN * CC / 4 + 255) / 256, 256, 0, stream>>>(
        x, mask, gamma, beta, mean, var, dst, h_bf, counts, epos);

    wconv_kernel<<<128, 256, 0, stream>>>(fc_w, fc_dst_w, wcat);

    scan1_kernel<<<SCAN_NBLK, 256, 0, stream>>>(counts, bsums);
    scan2_kernel<<<SCAN_NBLK, 256, 0, stream>>>(counts, bsums, row_ptr);

    dim3 ggrid((NN + 127) / 128, 2);
    gemm_mfma_kernel<<<ggrid, 512, 0, stream>>>(h_bf, wcat, attn_l, attn_r, feat, el, er);

    scatter_kernel<<<(EE + 255) / 256, 256, 0, stream>>>(src, dst, row_ptr, epos, sorted_src);

    agg_kernel<<<(NN + 3) / 4, 256, 0, stream>>>(row_ptr, sorted_src, el, er, feat, h_bf, bias, out);
}

// Round 6
// 180.188 us; speedup vs baseline: 5.9572x; 1.1882x over previous
//
#include <hip/hip_runtime.h>
#include <math.h>

#define NN 50000
#define CC 256
#define HH 4
#define DD 64
#define EE 800000
#define EPS 1e-5f
#define SLOPE 0.2f
#define SCAN_NBLK ((NN + 1023) / 1024)   // 49

typedef __attribute__((ext_vector_type(8))) short bf16x8;
typedef __attribute__((ext_vector_type(4))) float f32x4;

__device__ __forceinline__ unsigned short f2bf(float f) {
    unsigned int u = __float_as_uint(f);
    u += 0x7fffu + ((u >> 16) & 1u);          // RNE
    return (unsigned short)(u >> 16);
}
__device__ __forceinline__ float bflo(unsigned int u) { return __uint_as_float(u << 16); }
__device__ __forceinline__ float bfhi(unsigned int u) { return __uint_as_float(u & 0xffff0000u); }

#define GLDS16(g, l)                                                                   \
    __builtin_amdgcn_global_load_lds(                                                  \
        (const __attribute__((address_space(1))) unsigned int*)(g),                    \
        (__attribute__((address_space(3))) unsigned int*)(l), 16, 0, 0)

// ---------------- K1: BN -> ReLU -> mask -> h_bf16; fused dst histogram + edge pos ----------------
__global__ void bn_relu_kernel(const float* __restrict__ x, const float* __restrict__ mask,
                               const float* __restrict__ gamma, const float* __restrict__ beta,
                               const float* __restrict__ mean, const float* __restrict__ var,
                               const int* __restrict__ dst, unsigned short* __restrict__ h_bf,
                               int* __restrict__ counts, int* __restrict__ epos) {
    int i = blockIdx.x * 256 + threadIdx.x;          // float4 index, N*C/4 total
    const int total = NN * CC / 4;
    if (i >= total) return;
    float4 xv = ((const float4*)x)[i];
    float4 mv = ((const float4*)mask)[i];
    int c0 = (i & (CC / 4 - 1)) * 4;
    float4 hv;
    {
        float s = gamma[c0 + 0] * rsqrtf(var[c0 + 0] + EPS);
        float v = (xv.x - mean[c0 + 0]) * s + beta[c0 + 0];
        hv.x = fmaxf(v, 0.f) * mv.x;
    }
    {
        float s = gamma[c0 + 1] * rsqrtf(var[c0 + 1] + EPS);
        float v = (xv.y - mean[c0 + 1]) * s + beta[c0 + 1];
        hv.y = fmaxf(v, 0.f) * mv.y;
    }
    {
        float s = gamma[c0 + 2] * rsqrtf(var[c0 + 2] + EPS);
        float v = (xv.z - mean[c0 + 2]) * s + beta[c0 + 2];
        hv.z = fmaxf(v, 0.f) * mv.z;
    }
    {
        float s = gamma[c0 + 3] * rsqrtf(var[c0 + 3] + EPS);
        float v = (xv.w - mean[c0 + 3]) * s + beta[c0 + 3];
        hv.w = fmaxf(v, 0.f) * mv.w;
    }
    ushort4 hb;
    hb.x = f2bf(hv.x); hb.y = f2bf(hv.y); hb.z = f2bf(hv.z); hb.w = f2bf(hv.w);
    ((ushort4*)h_bf)[i] = hb;
    if (i < EE) epos[i] = atomicAdd(&counts[dst[i]], 1);   // histogram + per-edge slot
}

// ---------------- W conversion ----------------
__global__ void wconv_kernel(const float* __restrict__ fc_w, const float* __restrict__ fc_dst_w,
                             unsigned short* __restrict__ wcat) {
    int i = blockIdx.x * 256 + threadIdx.x;
    float4 v = (i < 16384) ? ((const float4*)fc_w)[i] : ((const float4*)fc_dst_w)[i - 16384];
    ushort4 o;
    o.x = f2bf(v.x); o.y = f2bf(v.y); o.z = f2bf(v.z); o.w = f2bf(v.w);
    ((ushort4*)wcat)[i] = o;
}

// ---------------- K2: feat = h_bf @ wcat^T (MFMA, LDS-staged m97 structure) ----------------
// 256 thr = 4 waves (2x2); block tile 128x128; wave 64x64 = 4x4 16x16x32 frags.
// Staging: global_load_lds width 16, LDS linear [row][64] bf16 (lane l -> base + l*16B).
__global__ __launch_bounds__(256) void gemm_mfma_kernel(const unsigned short* __restrict__ A,
                                                        const unsigned short* __restrict__ B,
                                                        const float* __restrict__ attn_l,
                                                        const float* __restrict__ attn_r,
                                                        unsigned short* __restrict__ feat,
                                                        float* __restrict__ el,
                                                        float* __restrict__ er) {
    __shared__ unsigned short sA[128 * 64];    // [row 0..127][k 0..63]
    __shared__ unsigned short sB[128 * 64];    // [col 0..127][k 0..63]

    const int wave = threadIdx.x >> 6;
    const int lane = threadIdx.x & 63;
    const int wm = wave >> 1, wn = wave & 1;
    const int brow = blockIdx.x * 128;
    const int bcol = blockIdx.y * 128;
    const int lr = lane & 15;
    const int lk = (lane >> 4) * 8;

    // staging geometry: chunk = it*4+wave covers rows chunk*8..chunk*8+7
    const int srow = lane >> 3;                // 0..7 within chunk
    const int scol = (lane & 7) * 8;           // k-elem base (16B)

    f32x4 acc[4][4] = {};

    for (int kt = 0; kt < 256; kt += 64) {
#pragma unroll
        for (int it = 0; it < 4; ++it) {
            int chunk = it * 4 + wave;         // 0..15
            int row = chunk * 8 + srow;        // 0..127
            GLDS16(A + (size_t)(brow + row) * 256 + kt + scol, &sA[chunk * 512]);
        }
#pragma unroll
        for (int it = 0; it < 4; ++it) {
            int chunk = it * 4 + wave;
            int row = chunk * 8 + srow;
            GLDS16(B + (size_t)(bcol + row) * 256 + kt + scol, &sB[chunk * 512]);
        }
        __syncthreads();                        // drains vmcnt (global_load_lds) too
#pragma unroll
        for (int ks = 0; ks < 2; ++ks) {
            bf16x8 a[4], b[4];
#pragma unroll
            for (int i = 0; i < 4; ++i)
                a[i] = *(const bf16x8*)&sA[(wm * 64 + i * 16 + lr) * 64 + ks * 32 + lk];
#pragma unroll
            for (int j = 0; j < 4; ++j)
                b[j] = *(const bf16x8*)&sB[(wn * 64 + j * 16 + lr) * 64 + ks * 32 + lk];
#pragma unroll
            for (int i = 0; i < 4; ++i)
#pragma unroll
                for (int j = 0; j < 4; ++j)
                    acc[i][j] = __builtin_amdgcn_mfma_f32_16x16x32_bf16(a[i], b[j], acc[i][j], 0, 0, 0);
        }
        __syncthreads();
    }

    const int m0 = brow + wm * 64;
    const int n0 = bcol + wn * 64;
    const int orow = (lane >> 4) * 4;          // C/D: col = lane&15, row = (lane>>4)*4 + reg
#pragma unroll
    for (int i = 0; i < 4; ++i) {
#pragma unroll
        for (int r = 0; r < 4; ++r) {
            int gr = m0 + i * 16 + orow + r;
            if (gr < NN) {
#pragma unroll
                for (int j = 0; j < 4; ++j)
                    feat[(size_t)gr * 512 + n0 + j * 16 + lr] = f2bf(acc[i][j][r]);
            }
        }
    }

    // ---- fused el/er: this wave's 64 cols = head (cb&3) of attn_l (cb<4) or attn_r ----
    const int cb = n0 >> 6;                    // 0..7
    const float* attn = (cb < 4) ? attn_l : attn_r;
    float* ep = (cb < 4) ? el : er;
    const int head = cb & 3;
    float coef[4];
#pragma unroll
    for (int j = 0; j < 4; ++j) coef[j] = attn[head * 64 + j * 16 + lr];

    float pv[16];
#pragma unroll
    for (int i = 0; i < 4; ++i)
#pragma unroll
        for (int r = 0; r < 4; ++r)
            pv[i * 4 + r] = acc[i][0][r] * coef[0] + acc[i][1][r] * coef[1] +
                            acc[i][2][r] * coef[2] + acc[i][3][r] * coef[3];
#pragma unroll
    for (int msk = 1; msk < 16; msk <<= 1)
#pragma unroll
        for (int k = 0; k < 16; ++k)
            pv[k] += __shfl_xor(pv[k], msk, 64);
    float sel = pv[0];
#pragma unroll
    for (int k = 1; k < 16; ++k)
        if (lr == k) sel = pv[k];
    int gr = m0 + (lr >> 2) * 16 + orow + (lr & 3);
    if (gr < NN) ep[gr * 4 + head] = sel;
}

// ---------------- Scan phase 1 ----------------
__global__ __launch_bounds__(256) void scan1_kernel(const int* __restrict__ counts,
                                                    int* __restrict__ bsums) {
    __shared__ int lds[256];
    int b = blockIdx.x, t = threadIdx.x;
    int base = b * 1024 + t * 4;
    int s = 0;
    if (base < NN) {
        int4 v = *(const int4*)(counts + base);
        s = v.x + v.y + v.z + v.w;
    }
    lds[t] = s;
    __syncthreads();
#pragma unroll
    for (int off = 128; off; off >>= 1) {
        if (t < off) lds[t] += lds[t + off];
        __syncthreads();
    }
    if (t == 0) bsums[b] = lds[0];
}

// ---------------- Scan phase 2 ----------------
__global__ __launch_bounds__(256) void scan2_kernel(const int* __restrict__ counts,
                                                    const int* __restrict__ bsums,
                                                    int* __restrict__ row_ptr) {
    __shared__ int lds[256];
    __shared__ int soff;
    int b = blockIdx.x, t = threadIdx.x;
    if (t < 64) {
        int p = (t < b) ? bsums[t] : 0;
#pragma unroll
        for (int off = 32; off; off >>= 1) p += __shfl_down(p, off, 64);
        if (t == 0) soff = p;
    }
    int base = b * 1024 + t * 4;
    int4 v = {0, 0, 0, 0};
    if (base < NN) v = *(const int4*)(counts + base);
    int s = v.x + v.y + v.z + v.w;
    lds[t] = s;
    __syncthreads();
    for (int off = 1; off < 256; off <<= 1) {
        int tmp = (t >= off) ? lds[t - off] : 0;
        __syncthreads();
        lds[t] += tmp;
        __syncthreads();
    }
    if (base < NN) {
        int excl = lds[t] - s + soff;
        row_ptr[base] = excl;
        row_ptr[base + 1] = excl + v.x;
        row_ptr[base + 2] = excl + v.x + v.y;
        row_ptr[base + 3] = excl + v.x + v.y + v.z;
    }
    if (b == 0 && t == 0) row_ptr[NN] = EE;
}

// ---------------- Scatter (atomic-free) ----------------
__global__ void scatter_kernel(const int* __restrict__ src, const int* __restrict__ dst,
                               const int* __restrict__ row_ptr, const int* __restrict__ epos,
                               int* __restrict__ sorted_src) {
    int e = blockIdx.x * 256 + threadIdx.x;
    if (e >= EE) return;
    sorted_src[row_ptr[dst[e]] + epos[e]] = src[e];
}

// ---------------- K5: single-pass gather agg, 4-wide pipelined ----------------
__global__ __launch_bounds__(256) void agg_kernel(const int* __restrict__ row_ptr,
                                                  const int* __restrict__ sorted_src,
                                                  const float* __restrict__ el,
                                                  const float* __restrict__ er,
                                                  const unsigned short* __restrict__ feat,
                                                  const unsigned short* __restrict__ h_bf,
                                                  const float* __restrict__ bias,
                                                  float* __restrict__ out) {
    int node = blockIdx.x * 4 + (threadIdx.x >> 6);
    if (node >= NN) return;
    int lane = threadIdx.x & 63;
    int beg = row_ptr[node];
    int g = row_ptr[node + 1] - beg;
    int h2 = lane >> 4;
    float er2 = er[node * 4 + h2];
    const int* ss = sorted_src + beg;

    float den = 0.f;
    float a0 = 0.f, a1 = 0.f, a2 = 0.f, a3 = 0.f;
    int j = 0;
    for (; j + 4 <= g; j += 4) {
        int s0 = ss[j], s1 = ss[j + 1], s2 = ss[j + 2], s3 = ss[j + 3];
        float v0 = el[s0 * 4 + h2] + er2;
        float v1 = el[s1 * 4 + h2] + er2;
        float v2 = el[s2 * 4 + h2] + er2;
        float v3 = el[s3 * 4 + h2] + er2;
        uint2 q0 = ((const uint2*)(feat + (size_t)s0 * 512))[lane];
        uint2 q1 = ((const uint2*)(feat + (size_t)s1 * 512))[lane];
        uint2 q2 = ((const uint2*)(feat + (size_t)s2 * 512))[lane];
        uint2 q3 = ((const uint2*)(feat + (size_t)s3 * 512))[lane];
        v0 = (v0 > 0.f) ? v0 : SLOPE * v0; float c0 = __expf(v0);
        v1 = (v1 > 0.f) ? v1 : SLOPE * v1; float c1 = __expf(v1);
        v2 = (v2 > 0.f) ? v2 : SLOPE * v2; float c2 = __expf(v2);
        v3 = (v3 > 0.f) ? v3 : SLOPE * v3; float c3 = __expf(v3);
        den += (c0 + c1) + (c2 + c3);
        a0 = fmaf(c0, bflo(q0.x), a0); a1 = fmaf(c0, bfhi(q0.x), a1);
        a2 = fmaf(c0, bflo(q0.y), a2); a3 = fmaf(c0, bfhi(q0.y), a3);
        a0 = fmaf(c1, bflo(q1.x), a0); a1 = fmaf(c1, bfhi(q1.x), a1);
        a2 = fmaf(c1, bflo(q1.y), a2); a3 = fmaf(c1, bfhi(q1.y), a3);
        a0 = fmaf(c2, bflo(q2.x), a0); a1 = fmaf(c2, bfhi(q2.x), a1);
        a2 = fmaf(c2, bflo(q2.y), a2); a3 = fmaf(c2, bfhi(q2.y), a3);
        a0 = fmaf(c3, bflo(q3.x), a0); a1 = fmaf(c3, bfhi(q3.x), a1);
        a2 = fmaf(c3, bflo(q3.y), a2); a3 = fmaf(c3, bfhi(q3.y), a3);
    }
    for (; j < g; ++j) {
        int s = ss[j];
        float v = el[s * 4 + h2] + er2;
        uint2 q = ((const uint2*)(feat + (size_t)s * 512))[lane];
        v = (v > 0.f) ? v : SLOPE * v;
        float c = __expf(v);
        den += c;
        a0 = fmaf(c, bflo(q.x), a0); a1 = fmaf(c, bfhi(q.x), a1);
        a2 = fmaf(c, bflo(q.y), a2); a3 = fmaf(c, bfhi(q.y), a3);
    }
    float inv = (g > 0) ? 1.f / den : 0.f;

    uint2 hb = ((const uint2*)(h_bf + (size_t)node * 256))[lane];
    float4 bv = ((const float4*)bias)[lane];
    float4 o;
    o.x = bflo(hb.x) + bv.x + a0 * inv;
    o.y = bfhi(hb.x) + bv.y + a1 * inv;
    o.z = bflo(hb.y) + bv.z + a2 * inv;
    o.w = bfhi(hb.y) + bv.w + a3 * inv;
    ((float4*)(out + (size_t)node * 256))[lane] = o;
}

extern "C" void kernel_launch(void* const* d_in, const int* in_sizes, int n_in,
                              void* d_out, int out_size, void* d_ws, size_t ws_size,
                              hipStream_t stream) {
    const float* x        = (const float*)d_in[0];
    const int*   eidx     = (const int*)d_in[1];
    const float* mask     = (const float*)d_in[2];
    const float* gamma    = (const float*)d_in[3];
    const float* beta     = (const float*)d_in[4];
    const float* mean     = (const float*)d_in[5];
    const float* var      = (const float*)d_in[6];
    const float* fc_w     = (const float*)d_in[7];
    const float* fc_dst_w = (const float*)d_in[8];
    const float* attn_l   = (const float*)d_in[9];
    const float* attn_r   = (const float*)d_in[10];
    const float* bias     = (const float*)d_in[11];
    float* out = (float*)d_out;

    const int* src = eidx;
    const int* dst = eidx + EE;

    const size_t NPAD = 50048;                 // 391*128 rows
    unsigned short* h_bf = (unsigned short*)d_ws;                 // NPAD*256 bf16
    unsigned short* wcat = h_bf + NPAD * 256;                     // 512*256 bf16
    unsigned short* feat = wcat + 512 * 256;                      // NPAD*512 bf16
    float* el            = (float*)(feat + NPAD * 512);           // N*4
    float* er            = el + (size_t)NN * 4;                   // N*4
    int* counts          = (int*)(er + (size_t)NN * 4);           // N  (16B-aligned)
    int* row_ptr         = counts + NN;                           // N+1
    int* sorted_src      = row_ptr + NN + 1;                      // E
    int* epos            = sorted_src + EE;                       // E
    int* bsums           = epos + EE;                             // SCAN_NBLK

    hipMemsetAsync(counts, 0, (size_t)NN * sizeof(int), stream);

    bn_relu_kernel<<<(NN * CC / 4 + 255) / 256, 256, 0, stream>>>(
        x, mask, gamma, beta, mean, var, dst, h_bf, counts, epos);

    wconv_kernel<<<128, 256, 0, stream>>>(fc_w, fc_dst_w, wcat);

    scan1_kernel<<<SCAN_NBLK, 256, 0, stream>>>(counts, bsums);
    scan2_kernel<<<SCAN_NBLK, 256, 0, stream>>>(counts, bsums, row_ptr);

    dim3 ggrid((NN + 127) / 128, 4);
    gemm_mfma_kernel<<<ggrid, 256, 0, stream>>>(h_bf, wcat, attn_l, attn_r, feat, el, er);

    scatter_kernel<<<(EE + 255) / 256, 256, 0, stream>>>(src, dst, row_ptr, epos, sorted_src);

    agg_kernel<<<(NN + 3) / 4, 256, 0, stream>>>(row_ptr, sorted_src, el, er, feat, h_bf, bias, out);
}